// Round 1
// baseline (6354.461 us; speedup 1.0000x reference)
//
#include <hip/hip_runtime.h>
#include <math.h>

#define T_ 16
#define N_ 20000
#define E_ 320000
#define EN_ (E_ + N_)
#define B_ 16

// ---- monotone unsigned encoding for float atomic max ----
__device__ __forceinline__ unsigned encf(float f) {
    unsigned u = __float_as_uint(f);
    return (u & 0x80000000u) ? ~u : (u | 0x80000000u);
}
__device__ __forceinline__ float decf(unsigned u) {
    return (u & 0x80000000u) ? __uint_as_float(u & 0x7FFFFFFFu)
                             : __uint_as_float(~u);
}
__device__ __forceinline__ float lrelu(float v) { return v >= 0.f ? v : 0.2f * v; }

// ---- layer 1: h1 = x @ W1 (7->64), per-head attention dots ----
__global__ void k_h1(const float* __restrict__ x, const float* __restrict__ W1,
                     const float* __restrict__ as1, const float* __restrict__ ad1,
                     float* __restrict__ h1, float* __restrict__ a_s, float* __restrict__ a_d) {
    int gid = blockIdx.x * blockDim.x + threadIdx.x;
    int wave = gid >> 6, lane = gid & 63;
    if (wave >= T_ * N_) return;
    float xv = (lane < 7) ? x[wave * 7 + lane] : 0.f;
    float acc = 0.f;
#pragma unroll
    for (int k = 0; k < 7; ++k) {
        float xk = __shfl(xv, k);
        acc = fmaf(xk, W1[k * 64 + lane], acc);
    }
    h1[wave * 64 + lane] = acc;
    float s = acc * as1[lane];   // att flat [2*32] matches lane layout
    float d = acc * ad1[lane];
#pragma unroll
    for (int m = 1; m < 32; m <<= 1) { s += __shfl_xor(s, m); d += __shfl_xor(d, m); }
    if ((lane & 31) == 0) {
        a_s[wave * 2 + (lane >> 5)] = s;
        a_d[wave * 2 + (lane >> 5)] = d;
    }
}

// ---- layer 2: h2 = hin @ W2 (64->64), single-head attention dots ----
__global__ void k_h2(const float* __restrict__ hin, const float* __restrict__ W2,
                     const float* __restrict__ as2, const float* __restrict__ ad2,
                     float* __restrict__ h2, float* __restrict__ a_s, float* __restrict__ a_d) {
    __shared__ float Wl[64 * 64];
    for (int i = threadIdx.x; i < 4096; i += blockDim.x) Wl[i] = W2[i];
    __syncthreads();
    int gid = blockIdx.x * blockDim.x + threadIdx.x;
    int wave = gid >> 6, lane = gid & 63;
    if (wave >= T_ * N_) return;
    float xv = hin[wave * 64 + lane];
    float acc = 0.f;
#pragma unroll
    for (int k = 0; k < 64; ++k) {
        float xk = __shfl(xv, k);
        acc = fmaf(xk, Wl[k * 64 + lane], acc);
    }
    h2[wave * 64 + lane] = acc;
    float s = acc * as2[lane], d = acc * ad2[lane];
#pragma unroll
    for (int m = 1; m < 64; m <<= 1) { s += __shfl_xor(s, m); d += __shfl_xor(d, m); }
    if (lane == 0) { a_s[wave] = s; a_d[wave] = d; }
}

// ---- edge pass 1: segment max (atomic max on encoded float) ----
template <int HEADS>
__global__ void k_edge_max(const int* __restrict__ ei, const float* __restrict__ a_s,
                           const float* __restrict__ a_d, unsigned* __restrict__ m) {
    int idx = blockIdx.x * blockDim.x + threadIdx.x;
    if (idx >= T_ * EN_) return;
    int t = idx / EN_, j = idx - t * EN_;
    int src, dst;
    if (j < E_) { src = ei[t * 2 * E_ + j]; dst = ei[t * 2 * E_ + E_ + j]; }
    else { src = dst = j - E_; }
#pragma unroll
    for (int h = 0; h < HEADS; ++h) {
        float e = lrelu(a_s[(t * N_ + src) * HEADS + h] + a_d[(t * N_ + dst) * HEADS + h]);
        atomicMax(&m[(t * N_ + dst) * HEADS + h], encf(e));
    }
}

// ---- edge pass 2: denominators ----
template <int HEADS>
__global__ void k_edge_sum(const int* __restrict__ ei, const float* __restrict__ a_s,
                           const float* __restrict__ a_d, const unsigned* __restrict__ m,
                           float* __restrict__ dsum) {
    int idx = blockIdx.x * blockDim.x + threadIdx.x;
    if (idx >= T_ * EN_) return;
    int t = idx / EN_, j = idx - t * EN_;
    int src, dst;
    if (j < E_) { src = ei[t * 2 * E_ + j]; dst = ei[t * 2 * E_ + E_ + j]; }
    else { src = dst = j - E_; }
#pragma unroll
    for (int h = 0; h < HEADS; ++h) {
        int id = (t * N_ + dst) * HEADS + h;
        float e = lrelu(a_s[(t * N_ + src) * HEADS + h] + a_d[id]);
        float p = expf(e - decf(m[id]));
        atomicAdd(&dsum[id], p);
    }
}

// ---- edge pass 3: aggregate messages (wave per edge, lane = channel) ----
template <int HEADS>
__global__ void k_agg(const int* __restrict__ ei, const float* __restrict__ a_s,
                      const float* __restrict__ a_d, const unsigned* __restrict__ m,
                      const float* __restrict__ dsum, const float* __restrict__ hin,
                      float* __restrict__ out) {
    int gid = blockIdx.x * blockDim.x + threadIdx.x;
    int wave = gid >> 6, lane = gid & 63;
    if (wave >= T_ * EN_) return;
    int t = wave / EN_, j = wave - t * EN_;
    int src, dst;
    if (j < E_) { src = ei[t * 2 * E_ + j]; dst = ei[t * 2 * E_ + E_ + j]; }
    else { src = dst = j - E_; }
    int head = (HEADS == 2) ? (lane >> 5) : 0;
    int is = (t * N_ + src) * HEADS + head;
    int id = (t * N_ + dst) * HEADS + head;
    float e = lrelu(a_s[is] + a_d[id]);
    float alpha = expf(e - decf(m[id])) / (dsum[id] + 1e-16f);
    atomicAdd(&out[(t * N_ + dst) * 64 + lane], hin[(t * N_ + src) * 64 + lane] * alpha);
}

// ---- bias + ELU in place ----
__global__ void k_bias_elu(float* __restrict__ h, const float* __restrict__ b) {
    int idx = blockIdx.x * blockDim.x + threadIdx.x;
    if (idx >= T_ * N_ * 64) return;
    float v = h[idx] + b[idx & 63];
    h[idx] = v > 0.f ? v : expm1f(v);
}

// ---- bias + ELU + batch mean-pool (sums & counts) ----
__global__ void k_pool(const float* __restrict__ h, const float* __restrict__ b2,
                       const int* __restrict__ batch, float* __restrict__ sums,
                       float* __restrict__ cnt) {
    int gid = blockIdx.x * blockDim.x + threadIdx.x;
    int wave = gid >> 6, lane = gid & 63;
    if (wave >= T_ * N_) return;
    int t = wave / N_;
    int b = batch[wave];
    float v = h[wave * 64 + lane] + b2[lane];
    v = v > 0.f ? v : expm1f(v);
    atomicAdd(&sums[(t * B_ + b) * 64 + lane], v);
    if (lane == 0) atomicAdd(&cnt[t * B_ + b], 1.0f);
}

__global__ void k_emb(const float* __restrict__ sums, const float* __restrict__ cnt,
                      float* __restrict__ emb) {
    int idx = blockIdx.x * blockDim.x + threadIdx.x;
    if (idx >= T_ * B_ * 64) return;
    emb[idx] = sums[idx] / fmaxf(cnt[idx >> 6], 1.0f);
}

// ---- gx = emb @ Wih^T + bih for all t (parallel, independent of h) ----
__global__ void k_gx(const float* __restrict__ emb, const float* __restrict__ Wih,
                     const float* __restrict__ bih, float* __restrict__ gx) {
    int idx = blockIdx.x * blockDim.x + threadIdx.x;
    if (idx >= T_ * B_ * 192) return;
    int tb = idx / 192, g = idx - tb * 192;
    const float* er = emb + tb * 64;
    const float* wr = Wih + g * 64;
    float acc = bih[g];
#pragma unroll
    for (int k = 0; k < 64; ++k) acc = fmaf(er[k], wr[k], acc);
    gx[idx] = acc;
}

// ---- sequential GRU + classifier head (single block) ----
__global__ __launch_bounds__(1024) void k_gru(
    const float* __restrict__ gx_all, const float* __restrict__ Whh,
    const float* __restrict__ bhh, const float* __restrict__ Wc1,
    const float* __restrict__ bc1, const float* __restrict__ Wc2,
    const float* __restrict__ bc2, float* __restrict__ out) {
    __shared__ float Wh[192 * 64];
    __shared__ float hL[16 * 64];
    __shared__ float gh[16 * 192];
    __shared__ float hid[16 * 32];
    int tid = threadIdx.x;
    for (int i = tid; i < 192 * 64; i += 1024) Wh[i] = Whh[i];
    if (tid < 1024) { hL[tid] = 0.f; }
    __syncthreads();
    for (int t = 0; t < T_; ++t) {
        for (int idx = tid; idx < 16 * 192; idx += 1024) {
            int b = idx / 192, g = idx - b * 192;
            float acc = bhh[g];
            const float* wr = Wh + g * 64;
            const float* hr = hL + b * 64;
#pragma unroll
            for (int k = 0; k < 64; ++k) acc = fmaf(hr[k], wr[k], acc);
            gh[idx] = acc;
        }
        __syncthreads();
        const float* gxt = gx_all + t * 16 * 192;
        {
            int b = tid >> 6, c = tid & 63;
            if (tid < 1024) {
                float xr = gxt[b * 192 + c], xz = gxt[b * 192 + 64 + c], xn = gxt[b * 192 + 128 + c];
                float hr_ = gh[b * 192 + c], hz = gh[b * 192 + 64 + c], hn = gh[b * 192 + 128 + c];
                float r = 1.f / (1.f + expf(-(xr + hr_)));
                float z = 1.f / (1.f + expf(-(xz + hz)));
                float n = tanhf(xn + r * hn);
                hL[tid] = (1.f - z) * n + z * hL[tid];
            }
        }
        __syncthreads();
    }
    for (int idx = tid; idx < 16 * 32; idx += 1024) {
        int b = idx >> 5, j = idx & 31;
        float acc = bc1[j];
#pragma unroll
        for (int k = 0; k < 64; ++k) acc = fmaf(hL[b * 64 + k], Wc1[k * 32 + j], acc);
        hid[idx] = fmaxf(acc, 0.f);
    }
    __syncthreads();
    if (tid < 16) {
        float acc = bc2[0];
#pragma unroll
        for (int k = 0; k < 32; ++k) acc = fmaf(hid[tid * 32 + k], Wc2[k], acc);
        out[tid] = acc;
    }
}

extern "C" void kernel_launch(void* const* d_in, const int* in_sizes, int n_in,
                              void* d_out, int out_size, void* d_ws, size_t ws_size,
                              hipStream_t stream) {
    const float* x   = (const float*)d_in[0];
    const int*   ei  = (const int*)d_in[1];
    const int* batch = (const int*)d_in[2];
    const float* W1  = (const float*)d_in[3];
    const float* as1 = (const float*)d_in[4];
    const float* ad1 = (const float*)d_in[5];
    const float* b1  = (const float*)d_in[6];
    const float* W2  = (const float*)d_in[7];
    const float* as2 = (const float*)d_in[8];
    const float* ad2 = (const float*)d_in[9];
    const float* b2  = (const float*)d_in[10];
    const float* Wih = (const float*)d_in[11];
    const float* Whh = (const float*)d_in[12];
    const float* bih = (const float*)d_in[13];
    const float* bhh = (const float*)d_in[14];
    const float* Wc1 = (const float*)d_in[15];
    const float* bc1 = (const float*)d_in[16];
    const float* Wc2 = (const float*)d_in[17];
    const float* bc2 = (const float*)d_in[18];
    float* out = (float*)d_out;

    float* ws = (float*)d_ws;
    float*    hA   = ws;                       // T*N*64 = 20,480,000
    float*    hB   = hA + 20480000;            // 20,480,000
    float*    a_s  = hB + 20480000;            // 640,000
    float*    a_d  = a_s + 640000;             // 640,000
    unsigned* mArr = (unsigned*)(a_d + 640000);// 640,000
    float*    dArr = (float*)(mArr + 640000);  // 640,000
    float*    sums = dArr + 640000;            // 16,384
    float*    cnt  = sums + 16384;             // 256
    float*    emb  = cnt + 256;                // 16,384
    float*    gx   = emb + 16384;              // 49,152

    const int TN = T_ * N_;
    const int TEN = T_ * EN_;

    // init (ws is poisoned before every call)
    hipMemsetAsync(hB, 0, (size_t)20480000 * 4, stream);
    hipMemsetAsync(mArr, 0, (size_t)640000 * 4, stream);
    hipMemsetAsync(dArr, 0, (size_t)640000 * 4, stream);
    hipMemsetAsync(sums, 0, (size_t)(16384 + 256 + 16384) * 4, stream);

    // ---- layer 1 ----
    k_h1<<<(TN * 64 + 255) / 256, 256, 0, stream>>>(x, W1, as1, ad1, hA, a_s, a_d);
    k_edge_max<2><<<(TEN + 255) / 256, 256, 0, stream>>>(ei, a_s, a_d, mArr);
    k_edge_sum<2><<<(TEN + 255) / 256, 256, 0, stream>>>(ei, a_s, a_d, mArr, dArr);
    k_agg<2><<<(unsigned)(((long)TEN * 64 + 255) / 256), 256, 0, stream>>>(
        ei, a_s, a_d, mArr, dArr, hA, hB);
    k_bias_elu<<<(TN * 64 + 255) / 256, 256, 0, stream>>>(hB, b1);

    // ---- layer 2 ----
    k_h2<<<(TN * 64 + 255) / 256, 256, 0, stream>>>(hB, W2, as2, ad2, hA, a_s, a_d);
    hipMemsetAsync(mArr, 0, (size_t)640000 * 4, stream);
    hipMemsetAsync(dArr, 0, (size_t)640000 * 4, stream);
    hipMemsetAsync(hB, 0, (size_t)20480000 * 4, stream);
    k_edge_max<1><<<(TEN + 255) / 256, 256, 0, stream>>>(ei, a_s, a_d, mArr);
    k_edge_sum<1><<<(TEN + 255) / 256, 256, 0, stream>>>(ei, a_s, a_d, mArr, dArr);
    k_agg<1><<<(unsigned)(((long)TEN * 64 + 255) / 256), 256, 0, stream>>>(
        ei, a_s, a_d, mArr, dArr, hA, hB);

    // ---- pool + GRU + head ----
    k_pool<<<(TN * 64 + 255) / 256, 256, 0, stream>>>(hB, b2, batch, sums, cnt);
    k_emb<<<(T_ * B_ * 64 + 255) / 256, 256, 0, stream>>>(sums, cnt, emb);
    k_gx<<<(T_ * B_ * 192 + 255) / 256, 256, 0, stream>>>(emb, Wih, bih, gx);
    k_gru<<<1, 1024, 0, stream>>>(gx, Whh, bhh, Wc1, bc1, Wc2, bc2, out);
}

// Round 2
// 3622.759 us; speedup vs baseline: 1.7540x; 1.7540x over previous
//
#include <hip/hip_runtime.h>
#include <math.h>

#define T_ 16
#define N_ 20000
#define E_ 320000
#define EN_ (E_ + N_)
#define B_ 16

__device__ __forceinline__ float lrelu(float v) { return v >= 0.f ? v : 0.2f * v; }
__device__ __forceinline__ float elu(float v) { return v > 0.f ? v : expm1f(v); }

// ---- layer 1: h1 = x @ W1 (7->64), per-head attention dots ----
__global__ void k_h1(const float* __restrict__ x, const float* __restrict__ W1,
                     const float* __restrict__ as1, const float* __restrict__ ad1,
                     float* __restrict__ h1, float* __restrict__ a_s, float* __restrict__ a_d) {
    int gid = blockIdx.x * blockDim.x + threadIdx.x;
    int wave = gid >> 6, lane = gid & 63;
    if (wave >= T_ * N_) return;
    float xv = (lane < 7) ? x[wave * 7 + lane] : 0.f;
    float acc = 0.f;
#pragma unroll
    for (int k = 0; k < 7; ++k) {
        float xk = __shfl(xv, k);
        acc = fmaf(xk, W1[k * 64 + lane], acc);
    }
    h1[wave * 64 + lane] = acc;
    float s = acc * as1[lane];
    float d = acc * ad1[lane];
#pragma unroll
    for (int m = 1; m < 32; m <<= 1) { s += __shfl_xor(s, m); d += __shfl_xor(d, m); }
    if ((lane & 31) == 0) {
        a_s[wave * 2 + (lane >> 5)] = s;
        a_d[wave * 2 + (lane >> 5)] = d;
    }
}

// ---- fused edge pass: out[dst] += exp(e)*h[src]; den[dst] += exp(e) ----
template <int HEADS>
__global__ void k_edge(const int* __restrict__ ei, const float* __restrict__ a_s,
                       const float* __restrict__ a_d, const float* __restrict__ hin,
                       float* __restrict__ out, float* __restrict__ den) {
    int gid = blockIdx.x * blockDim.x + threadIdx.x;
    int wave = gid >> 6, lane = gid & 63;
    if (wave >= T_ * EN_) return;
    int t = wave / EN_, j = wave - t * EN_;
    int src, dst;
    if (j < E_) { src = ei[t * 2 * E_ + j]; dst = ei[t * 2 * E_ + E_ + j]; }
    else { src = dst = j - E_; }
    int head = (HEADS == 2) ? (lane >> 5) : 0;
    float e = lrelu(a_s[(t * N_ + src) * HEADS + head] + a_d[(t * N_ + dst) * HEADS + head]);
    float p = expf(e);
    float hv = hin[(t * N_ + src) * 64 + lane];
    atomicAdd(&out[(t * N_ + dst) * 64 + lane], p * hv);
    if (HEADS == 2) {
        if ((lane & 31) == 0) atomicAdd(&den[(t * N_ + dst) * 2 + head], p);
    } else {
        if (lane == 0) atomicAdd(&den[t * N_ + dst], p);
    }
}

// ---- layer 2 GEMM, input = elu(msg/den + b1) applied on the fly ----
__global__ void k_h2(const float* __restrict__ msg, const float* __restrict__ den1,
                     const float* __restrict__ b1, const float* __restrict__ W2,
                     const float* __restrict__ as2, const float* __restrict__ ad2,
                     float* __restrict__ h2, float* __restrict__ a_s, float* __restrict__ a_d) {
    __shared__ float Wl[64 * 64];
    for (int i = threadIdx.x; i < 4096; i += blockDim.x) Wl[i] = W2[i];
    __syncthreads();
    int gid = blockIdx.x * blockDim.x + threadIdx.x;
    int wave = gid >> 6, lane = gid & 63;
    if (wave >= T_ * N_) return;
    float dv = den1[wave * 2 + (lane >> 5)];
    float xv = elu(msg[wave * 64 + lane] / (dv + 1e-16f) + b1[lane]);
    float acc = 0.f;
#pragma unroll
    for (int k = 0; k < 64; ++k) {
        float xk = __shfl(xv, k);
        acc = fmaf(xk, Wl[k * 64 + lane], acc);
    }
    h2[wave * 64 + lane] = acc;
    float s = acc * as2[lane], d = acc * ad2[lane];
#pragma unroll
    for (int m = 1; m < 64; m <<= 1) { s += __shfl_xor(s, m); d += __shfl_xor(d, m); }
    if (lane == 0) { a_s[wave] = s; a_d[wave] = d; }
}

// ---- final norm + bias + ELU + sorted-batch mean-pool (register-run accumulation) ----
// block = 256 threads (4 waves); each wave handles 64 contiguous nodes of one frame.
__global__ void k_pool(const float* __restrict__ msg, const float* __restrict__ den2,
                       const float* __restrict__ b2, const int* __restrict__ batch,
                       float* __restrict__ sums, float* __restrict__ cnt) {
    int wid = (blockIdx.x * blockDim.x + threadIdx.x) >> 6;
    int lane = threadIdx.x & 63;
    const int WPF = (N_ + 63) / 64;              // waves per frame = 313
    int t = wid / WPF, w = wid - t * WPF;
    if (t >= T_) return;
    int n0 = w * 64, n1 = min(n0 + 64, N_);
    float acc = 0.f, cacc = 0.f;
    int cur_b = batch[t * N_ + n0];
    for (int n = n0; n < n1; ++n) {
        int b = batch[t * N_ + n];
        if (b != cur_b) {
            atomicAdd(&sums[(t * B_ + cur_b) * 64 + lane], acc);
            if (lane == 0) atomicAdd(&cnt[t * B_ + cur_b], cacc);
            acc = 0.f; cacc = 0.f; cur_b = b;
        }
        int idx = t * N_ + n;
        float v = msg[idx * 64 + lane] / (den2[idx] + 1e-16f) + b2[lane];
        acc += elu(v);
        cacc += 1.f;
    }
    atomicAdd(&sums[(t * B_ + cur_b) * 64 + lane], acc);
    if (lane == 0) atomicAdd(&cnt[t * B_ + cur_b], cacc);
}

__global__ void k_emb(const float* __restrict__ sums, const float* __restrict__ cnt,
                      float* __restrict__ emb) {
    int idx = blockIdx.x * blockDim.x + threadIdx.x;
    if (idx >= T_ * B_ * 64) return;
    emb[idx] = sums[idx] / fmaxf(cnt[idx >> 6], 1.0f);
}

// ---- gx = emb @ Wih^T + bih for all t ----
__global__ void k_gx(const float* __restrict__ emb, const float* __restrict__ Wih,
                     const float* __restrict__ bih, float* __restrict__ gx) {
    int idx = blockIdx.x * blockDim.x + threadIdx.x;
    if (idx >= T_ * B_ * 192) return;
    int tb = idx / 192, g = idx - tb * 192;
    const float* er = emb + tb * 64;
    const float* wr = Wih + g * 64;
    float acc = bih[g];
#pragma unroll
    for (int k = 0; k < 64; ++k) acc = fmaf(er[k], wr[k], acc);
    gx[idx] = acc;
}

// ---- sequential GRU + classifier head (single block); Wh padded stride 65 ----
__global__ __launch_bounds__(1024) void k_gru(
    const float* __restrict__ gx_all, const float* __restrict__ Whh,
    const float* __restrict__ bhh, const float* __restrict__ Wc1,
    const float* __restrict__ bc1, const float* __restrict__ Wc2,
    const float* __restrict__ bc2, float* __restrict__ out) {
    __shared__ float Wh[192 * 65];
    __shared__ float hL[16 * 64];
    __shared__ float gh[16 * 192];
    __shared__ float hid[16 * 32];
    int tid = threadIdx.x;
    for (int i = tid; i < 192 * 64; i += 1024) Wh[(i >> 6) * 65 + (i & 63)] = Whh[i];
    hL[tid] = 0.f;
    __syncthreads();
    for (int t = 0; t < T_; ++t) {
        for (int idx = tid; idx < 16 * 192; idx += 1024) {
            int b = idx / 192, g = idx - b * 192;
            float acc = bhh[g];
            const float* wr = Wh + g * 65;
            const float* hr = hL + b * 64;
#pragma unroll
            for (int k = 0; k < 64; ++k) acc = fmaf(hr[k], wr[k], acc);
            gh[idx] = acc;
        }
        __syncthreads();
        const float* gxt = gx_all + t * 16 * 192;
        {
            int b = tid >> 6, c = tid & 63;
            float xr = gxt[b * 192 + c], xz = gxt[b * 192 + 64 + c], xn = gxt[b * 192 + 128 + c];
            float hr_ = gh[b * 192 + c], hz = gh[b * 192 + 64 + c], hn = gh[b * 192 + 128 + c];
            float r = 1.f / (1.f + expf(-(xr + hr_)));
            float z = 1.f / (1.f + expf(-(xz + hz)));
            float n = tanhf(xn + r * hn);
            hL[tid] = (1.f - z) * n + z * hL[tid];
        }
        __syncthreads();
    }
    for (int idx = tid; idx < 16 * 32; idx += 1024) {
        int b = idx >> 5, j = idx & 31;
        float acc = bc1[j];
#pragma unroll
        for (int k = 0; k < 64; ++k) acc = fmaf(hL[b * 64 + k], Wc1[k * 32 + j], acc);
        hid[idx] = fmaxf(acc, 0.f);
    }
    __syncthreads();
    if (tid < 16) {
        float acc = bc2[0];
#pragma unroll
        for (int k = 0; k < 32; ++k) acc = fmaf(hid[tid * 32 + k], Wc2[k], acc);
        out[tid] = acc;
    }
}

extern "C" void kernel_launch(void* const* d_in, const int* in_sizes, int n_in,
                              void* d_out, int out_size, void* d_ws, size_t ws_size,
                              hipStream_t stream) {
    const float* x   = (const float*)d_in[0];
    const int*   ei  = (const int*)d_in[1];
    const int* batch = (const int*)d_in[2];
    const float* W1  = (const float*)d_in[3];
    const float* as1 = (const float*)d_in[4];
    const float* ad1 = (const float*)d_in[5];
    const float* b1  = (const float*)d_in[6];
    const float* W2  = (const float*)d_in[7];
    const float* as2 = (const float*)d_in[8];
    const float* ad2 = (const float*)d_in[9];
    const float* b2  = (const float*)d_in[10];
    const float* Wih = (const float*)d_in[11];
    const float* Whh = (const float*)d_in[12];
    const float* bih = (const float*)d_in[13];
    const float* bhh = (const float*)d_in[14];
    const float* Wc1 = (const float*)d_in[15];
    const float* bc1 = (const float*)d_in[16];
    const float* Wc2 = (const float*)d_in[17];
    const float* bc2 = (const float*)d_in[18];
    float* out = (float*)d_out;

    float* ws = (float*)d_ws;
    float* hA   = ws;                    // 20,480,000  (h1 / h2)
    float* hB   = hA + 20480000;         // 20,480,000  (msg accumulators)
    float* a_s  = hB + 20480000;         // 640,000
    float* a_d  = a_s + 640000;          // 640,000
    float* den1 = a_d + 640000;          // 640,000 (T*N*2)
    float* den2 = den1 + 640000;         // 320,000 (T*N)
    float* sums = den2 + 320000;         // 16,384
    float* cnt  = sums + 16384;          // 256
    float* emb  = cnt + 256;             // 16,384
    float* gx   = emb + 16384;           // 49,152

    const int TN = T_ * N_;
    const int TEN = T_ * EN_;

    // zero accumulators (ws is re-poisoned before every call)
    hipMemsetAsync(hB, 0, (size_t)20480000 * 4, stream);
    hipMemsetAsync(den1, 0, (size_t)(640000 + 320000) * 4, stream);
    hipMemsetAsync(sums, 0, (size_t)(16384 + 256) * 4, stream);

    // ---- layer 1 ----
    k_h1<<<(TN * 64 + 255) / 256, 256, 0, stream>>>(x, W1, as1, ad1, hA, a_s, a_d);
    k_edge<2><<<(TEN * 64) / 256, 256, 0, stream>>>(ei, a_s, a_d, hA, hB, den1);

    // ---- layer 2 (k_h2 consumes hB then we reuse it as the layer-2 accumulator) ----
    k_h2<<<(TN * 64 + 255) / 256, 256, 0, stream>>>(hB, den1, b1, W2, as2, ad2, hA, a_s, a_d);
    hipMemsetAsync(hB, 0, (size_t)20480000 * 4, stream);
    k_edge<1><<<(TEN * 64) / 256, 256, 0, stream>>>(ei, a_s, a_d, hA, hB, den2);

    // ---- pool + GRU + head ----
    {
        const int WPF = (N_ + 63) / 64;  // 313 waves per frame
        int waves = T_ * WPF;
        k_pool<<<(waves * 64 + 255) / 256, 256, 0, stream>>>(hB, den2, b2, batch, sums, cnt);
    }
    k_emb<<<(T_ * B_ * 64 + 255) / 256, 256, 0, stream>>>(sums, cnt, emb);
    k_gx<<<(T_ * B_ * 192 + 255) / 256, 256, 0, stream>>>(emb, Wih, bih, gx);
    k_gru<<<1, 1024, 0, stream>>>(gx, Whh, bhh, Wc1, bc1, Wc2, bc2, out);
}

// Round 4
// 1848.813 us; speedup vs baseline: 3.4370x; 1.9595x over previous
//
#include <hip/hip_runtime.h>
#include <math.h>

#define T_ 16
#define N_ 20000
#define E_ 320000
#define EN_ (E_ + N_)
#define B_ 16

__device__ __forceinline__ float lrelu(float v) { return v >= 0.f ? v : 0.2f * v; }
__device__ __forceinline__ float elu(float v) { return v > 0.f ? v : expm1f(v); }

// ---- layer 1: h1 = x @ W1 (7->64), per-head attention dots ----
__global__ void k_h1(const float* __restrict__ x, const float* __restrict__ W1,
                     const float* __restrict__ as1, const float* __restrict__ ad1,
                     float* __restrict__ h1, float* __restrict__ a_s, float* __restrict__ a_d) {
    int gid = blockIdx.x * blockDim.x + threadIdx.x;
    int wave = gid >> 6, lane = gid & 63;
    if (wave >= T_ * N_) return;
    float xv = (lane < 7) ? x[wave * 7 + lane] : 0.f;
    float acc = 0.f;
#pragma unroll
    for (int k = 0; k < 7; ++k) {
        float xk = __shfl(xv, k);
        acc = fmaf(xk, W1[k * 64 + lane], acc);
    }
    h1[wave * 64 + lane] = acc;
    float s = acc * as1[lane];
    float d = acc * ad1[lane];
#pragma unroll
    for (int m = 1; m < 32; m <<= 1) { s += __shfl_xor(s, m); d += __shfl_xor(d, m); }
    if ((lane & 31) == 0) {
        a_s[wave * 2 + (lane >> 5)] = s;
        a_d[wave * 2 + (lane >> 5)] = d;
    }
}

// ---- CSR build: in-degree histogram (cur doubles as deg then cursor) ----
__global__ void k_deg(const int* __restrict__ ei, int* __restrict__ cnt) {
    int idx = blockIdx.x * blockDim.x + threadIdx.x;
    if (idx >= T_ * E_) return;
    int t = idx / E_, j = idx - t * E_;
    int dst = ei[t * 2 * E_ + E_ + j];
    atomicAdd(&cnt[t * N_ + dst], 1);
}

// ---- per-frame exclusive scan of (deg+1); writes rowptr and cursor ----
__global__ __launch_bounds__(1024) void k_scan(const int* __restrict__ deg,
                                               int* __restrict__ rowptr,
                                               int* __restrict__ cur) {
    int t = blockIdx.x;
    __shared__ int buf[1024];
    __shared__ int carryS;
    if (threadIdx.x == 0) { carryS = 0; rowptr[t * (N_ + 1)] = 0; }
    __syncthreads();
    for (int base = 0; base < N_; base += 1024) {
        int i = base + threadIdx.x;
        int v = (i < N_) ? deg[t * N_ + i] + 1 : 0;
        buf[threadIdx.x] = v;
        __syncthreads();
        for (int off = 1; off < 1024; off <<= 1) {
            int x = (threadIdx.x >= off) ? buf[threadIdx.x - off] : 0;
            __syncthreads();
            buf[threadIdx.x] += x;
            __syncthreads();
        }
        int incl = buf[threadIdx.x] + carryS;
        if (i < N_) { rowptr[t * (N_ + 1) + i + 1] = incl; cur[t * N_ + i] = incl - v; }
        __syncthreads();
        if (threadIdx.x == 1023) carryS = incl;
        __syncthreads();
    }
}

// ---- scatter src ids into CSR col array (self-loops appended as j>=E_) ----
__global__ void k_scatter(const int* __restrict__ ei, int* __restrict__ cur,
                          int* __restrict__ col) {
    int idx = blockIdx.x * blockDim.x + threadIdx.x;
    if (idx >= T_ * EN_) return;
    int t = idx / EN_, j = idx - t * EN_;
    int src, dst;
    if (j < E_) { src = ei[t * 2 * E_ + j]; dst = ei[t * 2 * E_ + E_ + j]; }
    else { src = dst = j - E_; }
    int pos = atomicAdd(&cur[t * N_ + dst], 1);
    col[t * EN_ + pos] = src;
}

// ---- gather-aggregate: wave per (t,node); fused softmax-norm + bias + ELU ----
template <int HEADS>
__global__ void k_agg(const int* __restrict__ rowptr, const int* __restrict__ col,
                      const float* __restrict__ a_s, const float* __restrict__ a_d,
                      const float* __restrict__ hin, const float* __restrict__ bias,
                      float* __restrict__ outp) {
    int gid = blockIdx.x * blockDim.x + threadIdx.x;
    int wave = gid >> 6, lane = gid & 63;
    if (wave >= T_ * N_) return;
    int t = wave / N_, n = wave - t * N_;
    int head = (HEADS == 2) ? (lane >> 5) : 0;
    float ad = a_d[wave * HEADS + head];
    int e0 = rowptr[t * (N_ + 1) + n], e1 = rowptr[t * (N_ + 1) + n + 1];
    const int* cb = col + (size_t)t * EN_;
    const float* hb = hin + (size_t)t * N_ * 64;
    const float* ab = a_s + (size_t)t * N_ * HEADS;
    float acc = 0.f, den = 0.f;
    int e = e0;
    for (; e + 1 < e1; e += 2) {
        int s0 = cb[e], s1 = cb[e + 1];
        float as0 = ab[s0 * HEADS + head];
        float as1 = ab[s1 * HEADS + head];
        float h0 = hb[s0 * 64 + lane];
        float h1 = hb[s1 * 64 + lane];
        float p0 = expf(lrelu(as0 + ad));
        float p1 = expf(lrelu(as1 + ad));
        den += p0 + p1;
        acc = fmaf(p0, h0, acc);
        acc = fmaf(p1, h1, acc);
    }
    if (e < e1) {
        int s0 = cb[e];
        float p0 = expf(lrelu(ab[s0 * HEADS + head] + ad));
        den += p0;
        acc = fmaf(p0, hb[s0 * 64 + lane], acc);
    }
    outp[(size_t)wave * 64 + lane] = elu(acc / (den + 1e-16f) + bias[lane]);
}

// ---- layer 2 GEMM on activated input ----
__global__ void k_h2(const float* __restrict__ xin, const float* __restrict__ W2,
                     const float* __restrict__ as2, const float* __restrict__ ad2,
                     float* __restrict__ h2, float* __restrict__ a_s, float* __restrict__ a_d) {
    __shared__ float Wl[64 * 64];
    for (int i = threadIdx.x; i < 4096; i += blockDim.x) Wl[i] = W2[i];
    __syncthreads();
    int gid = blockIdx.x * blockDim.x + threadIdx.x;
    int wave = gid >> 6, lane = gid & 63;
    if (wave >= T_ * N_) return;
    float xv = xin[wave * 64 + lane];
    float acc = 0.f;
#pragma unroll
    for (int k = 0; k < 64; ++k) {
        float xk = __shfl(xv, k);
        acc = fmaf(xk, Wl[k * 64 + lane], acc);
    }
    h2[wave * 64 + lane] = acc;
    float s = acc * as2[lane], d = acc * ad2[lane];
#pragma unroll
    for (int m = 1; m < 64; m <<= 1) { s += __shfl_xor(s, m); d += __shfl_xor(d, m); }
    if (lane == 0) { a_s[wave] = s; a_d[wave] = d; }
}

// ---- sorted-batch mean-pool over activated node features ----
__global__ void k_pool(const float* __restrict__ hact, const int* __restrict__ batch,
                       float* __restrict__ sums, float* __restrict__ cnt) {
    int wid = (blockIdx.x * blockDim.x + threadIdx.x) >> 6;
    int lane = threadIdx.x & 63;
    const int WPF = (N_ + 63) / 64;
    int t = wid / WPF, w = wid - t * WPF;
    if (t >= T_) return;
    int n0 = w * 64, n1 = min(n0 + 64, N_);
    float acc = 0.f, cacc = 0.f;
    int cur_b = batch[t * N_ + n0];
    for (int n = n0; n < n1; ++n) {
        int b = batch[t * N_ + n];
        if (b != cur_b) {
            atomicAdd(&sums[(t * B_ + cur_b) * 64 + lane], acc);
            if (lane == 0) atomicAdd(&cnt[t * B_ + cur_b], cacc);
            acc = 0.f; cacc = 0.f; cur_b = b;
        }
        acc += hact[(size_t)(t * N_ + n) * 64 + lane];
        cacc += 1.f;
    }
    atomicAdd(&sums[(t * B_ + cur_b) * 64 + lane], acc);
    if (lane == 0) atomicAdd(&cnt[t * B_ + cur_b], cacc);
}

__global__ void k_emb(const float* __restrict__ sums, const float* __restrict__ cnt,
                      float* __restrict__ emb) {
    int idx = blockIdx.x * blockDim.x + threadIdx.x;
    if (idx >= T_ * B_ * 64) return;
    emb[idx] = sums[idx] / fmaxf(cnt[idx >> 6], 1.0f);
}

__global__ void k_gx(const float* __restrict__ emb, const float* __restrict__ Wih,
                     const float* __restrict__ bih, float* __restrict__ gx) {
    int idx = blockIdx.x * blockDim.x + threadIdx.x;
    if (idx >= T_ * B_ * 192) return;
    int tb = idx / 192, g = idx - tb * 192;
    const float* er = emb + tb * 64;
    const float* wr = Wih + g * 64;
    float acc = bih[g];
#pragma unroll
    for (int k = 0; k < 64; ++k) acc = fmaf(er[k], wr[k], acc);
    gx[idx] = acc;
}

// ---- sequential GRU + classifier head (single block); Wh padded stride 65 ----
__global__ __launch_bounds__(1024) void k_gru(
    const float* __restrict__ gx_all, const float* __restrict__ Whh,
    const float* __restrict__ bhh, const float* __restrict__ Wc1,
    const float* __restrict__ bc1, const float* __restrict__ Wc2,
    const float* __restrict__ bc2, float* __restrict__ out) {
    __shared__ float Wh[192 * 65];
    __shared__ float hL[16 * 64];
    __shared__ float gh[16 * 192];
    __shared__ float hid[16 * 32];
    int tid = threadIdx.x;
    for (int i = tid; i < 192 * 64; i += 1024) Wh[(i >> 6) * 65 + (i & 63)] = Whh[i];
    hL[tid] = 0.f;
    __syncthreads();
    for (int t = 0; t < T_; ++t) {
        for (int idx = tid; idx < 16 * 192; idx += 1024) {
            int b = idx / 192, g = idx - b * 192;
            float acc = bhh[g];
            const float* wr = Wh + g * 65;
            const float* hr = hL + b * 64;
#pragma unroll
            for (int k = 0; k < 64; ++k) acc = fmaf(hr[k], wr[k], acc);
            gh[idx] = acc;
        }
        __syncthreads();
        const float* gxt = gx_all + t * 16 * 192;
        {
            int b = tid >> 6, c = tid & 63;
            float xr = gxt[b * 192 + c], xz = gxt[b * 192 + 64 + c], xn = gxt[b * 192 + 128 + c];
            float hr_ = gh[b * 192 + c], hz = gh[b * 192 + 64 + c], hn = gh[b * 192 + 128 + c];
            float r = 1.f / (1.f + expf(-(xr + hr_)));
            float z = 1.f / (1.f + expf(-(xz + hz)));
            float n = tanhf(xn + r * hn);
            hL[tid] = (1.f - z) * n + z * hL[tid];
        }
        __syncthreads();
    }
    for (int idx = tid; idx < 16 * 32; idx += 1024) {
        int b = idx >> 5, j = idx & 31;
        float acc = bc1[j];
#pragma unroll
        for (int k = 0; k < 64; ++k) acc = fmaf(hL[b * 64 + k], Wc1[k * 32 + j], acc);
        hid[idx] = fmaxf(acc, 0.f);
    }
    __syncthreads();
    if (tid < 16) {
        float acc = bc2[0];
#pragma unroll
        for (int k = 0; k < 32; ++k) acc = fmaf(hid[tid * 32 + k], Wc2[k], acc);
        out[tid] = acc;
    }
}

extern "C" void kernel_launch(void* const* d_in, const int* in_sizes, int n_in,
                              void* d_out, int out_size, void* d_ws, size_t ws_size,
                              hipStream_t stream) {
    const float* x   = (const float*)d_in[0];
    const int*   ei  = (const int*)d_in[1];
    const int* batch = (const int*)d_in[2];
    const float* W1  = (const float*)d_in[3];
    const float* as1 = (const float*)d_in[4];
    const float* ad1 = (const float*)d_in[5];
    const float* b1  = (const float*)d_in[6];
    const float* W2  = (const float*)d_in[7];
    const float* as2 = (const float*)d_in[8];
    const float* ad2 = (const float*)d_in[9];
    const float* b2  = (const float*)d_in[10];
    const float* Wih = (const float*)d_in[11];
    const float* Whh = (const float*)d_in[12];
    const float* bih = (const float*)d_in[13];
    const float* bhh = (const float*)d_in[14];
    const float* Wc1 = (const float*)d_in[15];
    const float* bc1 = (const float*)d_in[16];
    const float* Wc2 = (const float*)d_in[17];
    const float* bc2 = (const float*)d_in[18];
    float* out = (float*)d_out;

    float* ws = (float*)d_ws;
    float* hA     = ws;                      // 20,480,000 (h1 / h2)
    float* hX     = hA + 20480000;           // 20,480,000 (activated xin / out2)
    float* a_s    = hX + 20480000;           // 640,000
    float* a_d    = a_s + 640000;            // 640,000
    int*   rowptr = (int*)(a_d + 640000);    // 16*(N+1) = 320,016 (pad to 320,032)
    int*   cur    = rowptr + 320032;         // 320,000 (deg, then cursor)
    int*   col    = cur + 320000;            // 16*EN = 5,440,000
    float* sums   = (float*)(col + 5440000); // 16,384
    float* cnt    = sums + 16384;            // 256
    float* emb    = cnt + 256;               // 16,384
    float* gx     = emb + 16384;             // 49,152

    const int TN = T_ * N_;

    hipMemsetAsync(cur, 0, (size_t)320000 * 4, stream);
    hipMemsetAsync(sums, 0, (size_t)(16384 + 256) * 4, stream);

    // ---- CSR build (shared by both layers) ----
    k_deg<<<(T_ * E_ + 255) / 256, 256, 0, stream>>>(ei, cur);
    k_scan<<<T_, 1024, 0, stream>>>(cur, rowptr, cur);
    k_scatter<<<(T_ * EN_ + 255) / 256, 256, 0, stream>>>(ei, cur, col);

    // ---- layer 1 ----
    k_h1<<<(TN * 64 + 255) / 256, 256, 0, stream>>>(x, W1, as1, ad1, hA, a_s, a_d);
    k_agg<2><<<(TN * 64 + 255) / 256, 256, 0, stream>>>(rowptr, col, a_s, a_d, hA, b1, hX);

    // ---- layer 2 ----
    k_h2<<<(TN * 64 + 255) / 256, 256, 0, stream>>>(hX, W2, as2, ad2, hA, a_s, a_d);
    k_agg<1><<<(TN * 64 + 255) / 256, 256, 0, stream>>>(rowptr, col, a_s, a_d, hA, b2, hX);

    // ---- pool + GRU + head ----
    {
        const int WPF = (N_ + 63) / 64;
        int waves = T_ * WPF;
        k_pool<<<(waves * 64 + 255) / 256, 256, 0, stream>>>(hX, batch, sums, cnt);
    }
    k_emb<<<(T_ * B_ * 64 + 255) / 256, 256, 0, stream>>>(sums, cnt, emb);
    k_gx<<<(T_ * B_ * 192 + 255) / 256, 256, 0, stream>>>(emb, Wih, bih, gx);
    k_gru<<<1, 1024, 0, stream>>>(gx, Whh, bhh, Wc1, bc1, Wc2, bc2, out);
}

// Round 5
// 1590.151 us; speedup vs baseline: 3.9961x; 1.1627x over previous
//
#include <hip/hip_runtime.h>
#include <math.h>

#define T_ 16
#define N_ 20000
#define E_ 320000
#define EN_ (E_ + N_)
#define B_ 16

__device__ __forceinline__ float lrelu(float v) { return v >= 0.f ? v : 0.2f * v; }
__device__ __forceinline__ float elu(float v) { return v > 0.f ? v : expm1f(v); }
__device__ __forceinline__ float rdlane(float v, int k) {
    return __uint_as_float(__builtin_amdgcn_readlane(__float_as_uint(v), k));
}

// ---- layer 1: h1 = x @ W1 (7->64), per-head attention dots ----
// grid-stride wave-per-row; W1 column in 7 VGPRs; broadcast via v_readlane (VALU, not DS)
__global__ __launch_bounds__(256) void k_h1(
    const float* __restrict__ x, const float* __restrict__ W1,
    const float* __restrict__ as1, const float* __restrict__ ad1,
    float* __restrict__ h1, float* __restrict__ a_s, float* __restrict__ a_d) {
    int lane = threadIdx.x & 63;
    int wid = (blockIdx.x * blockDim.x + threadIdx.x) >> 6;
    int nw = (gridDim.x * blockDim.x) >> 6;
    float w[7];
#pragma unroll
    for (int k = 0; k < 7; ++k) w[k] = W1[k * 64 + lane];
    float asl = as1[lane], adl = ad1[lane];
    float xv = (wid < T_ * N_ && lane < 7) ? x[(size_t)wid * 7 + lane] : 0.f;
    for (int r = wid; r < T_ * N_; r += nw) {
        float xcur = xv;
        int rn = r + nw;
        if (rn < T_ * N_ && lane < 7) xv = x[(size_t)rn * 7 + lane];
        float acc = 0.f;
#pragma unroll
        for (int k = 0; k < 7; ++k) acc = fmaf(rdlane(xcur, k), w[k], acc);
        h1[(size_t)r * 64 + lane] = acc;
        float s = acc * asl, d = acc * adl;
#pragma unroll
        for (int m = 1; m < 32; m <<= 1) { s += __shfl_xor(s, m); d += __shfl_xor(d, m); }
        if ((lane & 31) == 0) {
            a_s[r * 2 + (lane >> 5)] = s;
            a_d[r * 2 + (lane >> 5)] = d;
        }
    }
}

// ---- CSR build: in-degree histogram (cur doubles as deg then cursor) ----
__global__ void k_deg(const int* __restrict__ ei, int* __restrict__ cnt) {
    int idx = blockIdx.x * blockDim.x + threadIdx.x;
    if (idx >= T_ * E_) return;
    int t = idx / E_, j = idx - t * E_;
    int dst = ei[t * 2 * E_ + E_ + j];
    atomicAdd(&cnt[t * N_ + dst], 1);
}

// ---- per-frame exclusive scan of (deg+1); writes rowptr and cursor ----
__global__ __launch_bounds__(1024) void k_scan(const int* __restrict__ deg,
                                               int* __restrict__ rowptr,
                                               int* __restrict__ cur) {
    int t = blockIdx.x;
    __shared__ int buf[1024];
    __shared__ int carryS;
    if (threadIdx.x == 0) { carryS = 0; rowptr[t * (N_ + 1)] = 0; }
    __syncthreads();
    for (int base = 0; base < N_; base += 1024) {
        int i = base + threadIdx.x;
        int v = (i < N_) ? deg[t * N_ + i] + 1 : 0;
        buf[threadIdx.x] = v;
        __syncthreads();
        for (int off = 1; off < 1024; off <<= 1) {
            int x = (threadIdx.x >= off) ? buf[threadIdx.x - off] : 0;
            __syncthreads();
            buf[threadIdx.x] += x;
            __syncthreads();
        }
        int incl = buf[threadIdx.x] + carryS;
        if (i < N_) { rowptr[t * (N_ + 1) + i + 1] = incl; cur[t * N_ + i] = incl - v; }
        __syncthreads();
        if (threadIdx.x == 1023) carryS = incl;
        __syncthreads();
    }
}

// ---- scatter src ids into CSR col array (self-loops appended as j>=E_) ----
__global__ void k_scatter(const int* __restrict__ ei, int* __restrict__ cur,
                          int* __restrict__ col) {
    int idx = blockIdx.x * blockDim.x + threadIdx.x;
    if (idx >= T_ * EN_) return;
    int t = idx / EN_, j = idx - t * EN_;
    int src, dst;
    if (j < E_) { src = ei[t * 2 * E_ + j]; dst = ei[t * 2 * E_ + E_ + j]; }
    else { src = dst = j - E_; }
    int pos = atomicAdd(&cur[t * N_ + dst], 1);
    col[t * EN_ + pos] = src;
}

// ---- gather-aggregate: wave per (t,node); fused softmax-norm + bias + ELU ----
template <int HEADS>
__global__ void k_agg(const int* __restrict__ rowptr, const int* __restrict__ col,
                      const float* __restrict__ a_s, const float* __restrict__ a_d,
                      const float* __restrict__ hin, const float* __restrict__ bias,
                      float* __restrict__ outp) {
    int gid = blockIdx.x * blockDim.x + threadIdx.x;
    int wave = gid >> 6, lane = gid & 63;
    if (wave >= T_ * N_) return;
    int t = wave / N_, n = wave - t * N_;
    int head = (HEADS == 2) ? (lane >> 5) : 0;
    float ad = a_d[wave * HEADS + head];
    int e0 = rowptr[t * (N_ + 1) + n], e1 = rowptr[t * (N_ + 1) + n + 1];
    const int* cb = col + (size_t)t * EN_;
    const float* hb = hin + (size_t)t * N_ * 64;
    const float* ab = a_s + (size_t)t * N_ * HEADS;
    float acc = 0.f, den = 0.f;
    int e = e0;
    for (; e + 1 < e1; e += 2) {
        int s0 = cb[e], s1 = cb[e + 1];
        float as0 = ab[s0 * HEADS + head];
        float as1 = ab[s1 * HEADS + head];
        float h0 = hb[s0 * 64 + lane];
        float h1 = hb[s1 * 64 + lane];
        float p0 = expf(lrelu(as0 + ad));
        float p1 = expf(lrelu(as1 + ad));
        den += p0 + p1;
        acc = fmaf(p0, h0, acc);
        acc = fmaf(p1, h1, acc);
    }
    if (e < e1) {
        int s0 = cb[e];
        float p0 = expf(lrelu(ab[s0 * HEADS + head] + ad));
        den += p0;
        acc = fmaf(p0, hb[s0 * 64 + lane], acc);
    }
    outp[(size_t)wave * 64 + lane] = elu(acc / (den + 1e-16f) + bias[lane]);
}

// ---- layer 2 GEMM: wave-per-row grid-stride; W2 column in 64 VGPRs; readlane broadcast ----
__global__ __launch_bounds__(256) void k_h2(
    const float* __restrict__ xin, const float* __restrict__ W2,
    const float* __restrict__ as2, const float* __restrict__ ad2,
    float* __restrict__ h2, float* __restrict__ a_s, float* __restrict__ a_d) {
    int lane = threadIdx.x & 63;
    int wid = (blockIdx.x * blockDim.x + threadIdx.x) >> 6;
    int nw = (gridDim.x * blockDim.x) >> 6;
    float w[64];
#pragma unroll
    for (int k = 0; k < 64; ++k) w[k] = W2[k * 64 + lane];
    float asl = as2[lane], adl = ad2[lane];
    float xv = (wid < T_ * N_) ? xin[(size_t)wid * 64 + lane] : 0.f;
    for (int r = wid; r < T_ * N_; r += nw) {
        float xcur = xv;
        int rn = r + nw;
        if (rn < T_ * N_) xv = xin[(size_t)rn * 64 + lane];
        float acc = 0.f;
#pragma unroll
        for (int k = 0; k < 64; ++k) acc = fmaf(rdlane(xcur, k), w[k], acc);
        h2[(size_t)r * 64 + lane] = acc;
        float s = acc * asl, d = acc * adl;
#pragma unroll
        for (int m = 1; m < 64; m <<= 1) { s += __shfl_xor(s, m); d += __shfl_xor(d, m); }
        if (lane == 0) { a_s[r] = s; a_d[r] = d; }
    }
}

// ---- sorted-batch mean-pool over activated node features ----
__global__ void k_pool(const float* __restrict__ hact, const int* __restrict__ batch,
                       float* __restrict__ sums, float* __restrict__ cnt) {
    int wid = (blockIdx.x * blockDim.x + threadIdx.x) >> 6;
    int lane = threadIdx.x & 63;
    const int WPF = (N_ + 63) / 64;
    int t = wid / WPF, w = wid - t * WPF;
    if (t >= T_) return;
    int n0 = w * 64, n1 = min(n0 + 64, N_);
    float acc = 0.f, cacc = 0.f;
    int cur_b = batch[t * N_ + n0];
    for (int n = n0; n < n1; ++n) {
        int b = batch[t * N_ + n];
        if (b != cur_b) {
            atomicAdd(&sums[(t * B_ + cur_b) * 64 + lane], acc);
            if (lane == 0) atomicAdd(&cnt[t * B_ + cur_b], cacc);
            acc = 0.f; cacc = 0.f; cur_b = b;
        }
        acc += hact[(size_t)(t * N_ + n) * 64 + lane];
        cacc += 1.f;
    }
    atomicAdd(&sums[(t * B_ + cur_b) * 64 + lane], acc);
    if (lane == 0) atomicAdd(&cnt[t * B_ + cur_b], cacc);
}

__global__ void k_emb(const float* __restrict__ sums, const float* __restrict__ cnt,
                      float* __restrict__ emb) {
    int idx = blockIdx.x * blockDim.x + threadIdx.x;
    if (idx >= T_ * B_ * 64) return;
    emb[idx] = sums[idx] / fmaxf(cnt[idx >> 6], 1.0f);
}

__global__ void k_gx(const float* __restrict__ emb, const float* __restrict__ Wih,
                     const float* __restrict__ bih, float* __restrict__ gx) {
    int idx = blockIdx.x * blockDim.x + threadIdx.x;
    if (idx >= T_ * B_ * 192) return;
    int tb = idx / 192, g = idx - tb * 192;
    const float* er = emb + tb * 64;
    const float* wr = Wih + g * 64;
    float acc = bih[g];
#pragma unroll
    for (int k = 0; k < 64; ++k) acc = fmaf(er[k], wr[k], acc);
    gx[idx] = acc;
}

// ---- sequential GRU + classifier head (single block); Wh padded stride 65 ----
__global__ __launch_bounds__(1024) void k_gru(
    const float* __restrict__ gx_all, const float* __restrict__ Whh,
    const float* __restrict__ bhh, const float* __restrict__ Wc1,
    const float* __restrict__ bc1, const float* __restrict__ Wc2,
    const float* __restrict__ bc2, float* __restrict__ out) {
    __shared__ float Wh[192 * 65];
    __shared__ float hL[16 * 64];
    __shared__ float gh[16 * 192];
    __shared__ float hid[16 * 32];
    int tid = threadIdx.x;
    for (int i = tid; i < 192 * 64; i += 1024) Wh[(i >> 6) * 65 + (i & 63)] = Whh[i];
    hL[tid] = 0.f;
    __syncthreads();
    for (int t = 0; t < T_; ++t) {
        for (int idx = tid; idx < 16 * 192; idx += 1024) {
            int b = idx / 192, g = idx - b * 192;
            float acc = bhh[g];
            const float* wr = Wh + g * 65;
            const float* hr = hL + b * 64;
#pragma unroll
            for (int k = 0; k < 64; ++k) acc = fmaf(hr[k], wr[k], acc);
            gh[idx] = acc;
        }
        __syncthreads();
        const float* gxt = gx_all + t * 16 * 192;
        {
            int b = tid >> 6, c = tid & 63;
            float xr = gxt[b * 192 + c], xz = gxt[b * 192 + 64 + c], xn = gxt[b * 192 + 128 + c];
            float hr_ = gh[b * 192 + c], hz = gh[b * 192 + 64 + c], hn = gh[b * 192 + 128 + c];
            float r = 1.f / (1.f + expf(-(xr + hr_)));
            float z = 1.f / (1.f + expf(-(xz + hz)));
            float n = tanhf(xn + r * hn);
            hL[tid] = (1.f - z) * n + z * hL[tid];
        }
        __syncthreads();
    }
    for (int idx = tid; idx < 16 * 32; idx += 1024) {
        int b = idx >> 5, j = idx & 31;
        float acc = bc1[j];
#pragma unroll
        for (int k = 0; k < 64; ++k) acc = fmaf(hL[b * 64 + k], Wc1[k * 32 + j], acc);
        hid[idx] = fmaxf(acc, 0.f);
    }
    __syncthreads();
    if (tid < 16) {
        float acc = bc2[0];
#pragma unroll
        for (int k = 0; k < 32; ++k) acc = fmaf(hid[tid * 32 + k], Wc2[k], acc);
        out[tid] = acc;
    }
}

extern "C" void kernel_launch(void* const* d_in, const int* in_sizes, int n_in,
                              void* d_out, int out_size, void* d_ws, size_t ws_size,
                              hipStream_t stream) {
    const float* x   = (const float*)d_in[0];
    const int*   ei  = (const int*)d_in[1];
    const int* batch = (const int*)d_in[2];
    const float* W1  = (const float*)d_in[3];
    const float* as1 = (const float*)d_in[4];
    const float* ad1 = (const float*)d_in[5];
    const float* b1  = (const float*)d_in[6];
    const float* W2  = (const float*)d_in[7];
    const float* as2 = (const float*)d_in[8];
    const float* ad2 = (const float*)d_in[9];
    const float* b2  = (const float*)d_in[10];
    const float* Wih = (const float*)d_in[11];
    const float* Whh = (const float*)d_in[12];
    const float* bih = (const float*)d_in[13];
    const float* bhh = (const float*)d_in[14];
    const float* Wc1 = (const float*)d_in[15];
    const float* bc1 = (const float*)d_in[16];
    const float* Wc2 = (const float*)d_in[17];
    const float* bc2 = (const float*)d_in[18];
    float* out = (float*)d_out;

    float* ws = (float*)d_ws;
    float* hA     = ws;                      // 20,480,000 (h1 / h2)
    float* hX     = hA + 20480000;           // 20,480,000 (activated xin / out2)
    float* a_s    = hX + 20480000;           // 640,000
    float* a_d    = a_s + 640000;            // 640,000
    int*   rowptr = (int*)(a_d + 640000);    // 16*(N+1) = 320,016 (pad to 320,032)
    int*   cur    = rowptr + 320032;         // 320,000 (deg, then cursor)
    int*   col    = cur + 320000;            // 16*EN = 5,440,000
    float* sums   = (float*)(col + 5440000); // 16,384
    float* cnt    = sums + 16384;            // 256
    float* emb    = cnt + 256;               // 16,384
    float* gx     = emb + 16384;             // 49,152

    const int TN = T_ * N_;

    hipMemsetAsync(cur, 0, (size_t)320000 * 4, stream);
    hipMemsetAsync(sums, 0, (size_t)(16384 + 256) * 4, stream);

    // ---- CSR build (shared by both layers) ----
    k_deg<<<(T_ * E_ + 255) / 256, 256, 0, stream>>>(ei, cur);
    k_scan<<<T_, 1024, 0, stream>>>(cur, rowptr, cur);
    k_scatter<<<(T_ * EN_ + 255) / 256, 256, 0, stream>>>(ei, cur, col);

    // ---- layer 1 ----
    k_h1<<<1024, 256, 0, stream>>>(x, W1, as1, ad1, hA, a_s, a_d);
    k_agg<2><<<(TN * 64 + 255) / 256, 256, 0, stream>>>(rowptr, col, a_s, a_d, hA, b1, hX);

    // ---- layer 2 ----
    k_h2<<<1024, 256, 0, stream>>>(hX, W2, as2, ad2, hA, a_s, a_d);
    k_agg<1><<<(TN * 64 + 255) / 256, 256, 0, stream>>>(rowptr, col, a_s, a_d, hA, b2, hX);

    // ---- pool + GRU + head ----
    {
        const int WPF = (N_ + 63) / 64;
        int waves = T_ * WPF;
        k_pool<<<(waves * 64 + 255) / 256, 256, 0, stream>>>(hX, batch, sums, cnt);
    }
    k_emb<<<(T_ * B_ * 64 + 255) / 256, 256, 0, stream>>>(sums, cnt, emb);
    k_gx<<<(T_ * B_ * 192 + 255) / 256, 256, 0, stream>>>(emb, Wih, bih, gx);
    k_gru<<<1, 1024, 0, stream>>>(gx, Whh, bhh, Wc1, bc1, Wc2, bc2, out);
}

// Round 6
// 1299.750 us; speedup vs baseline: 4.8890x; 1.2234x over previous
//
#include <hip/hip_runtime.h>
#include <math.h>

#define T_ 16
#define N_ 20000
#define E_ 320000
#define EN_ (E_ + N_)
#define B_ 16

__device__ __forceinline__ float lrelu(float v) { return v >= 0.f ? v : 0.2f * v; }
__device__ __forceinline__ float elu(float v) { return v > 0.f ? v : expm1f(v); }
__device__ __forceinline__ float rdlane(float v, int k) {
    return __uint_as_float(__builtin_amdgcn_readlane(__float_as_uint(v), k));
}

// Frame->XCD affinity: grid = 16*BPF blocks; 8 XCDs x 2 frames each.
// bid%8 selects XCD slot; within it, blocks alternate between its 2 frames.
__device__ __forceinline__ void frame_map(int bid, int* frame, int* local) {
    int blk = bid >> 3;
    *frame = (bid & 7) * 2 + (blk & 1);
    *local = blk >> 1;
}

// ---- layer 1: h1 = x @ W1 (7->64), per-head attention dots ----
__global__ __launch_bounds__(256) void k_h1(
    const float* __restrict__ x, const float* __restrict__ W1,
    const float* __restrict__ as1, const float* __restrict__ ad1,
    float* __restrict__ h1, float* __restrict__ a_s, float* __restrict__ a_d) {
    int lane = threadIdx.x & 63;
    int wid = (blockIdx.x * blockDim.x + threadIdx.x) >> 6;
    int nw = (gridDim.x * blockDim.x) >> 6;
    float w[7];
#pragma unroll
    for (int k = 0; k < 7; ++k) w[k] = W1[k * 64 + lane];
    float asl = as1[lane], adl = ad1[lane];
    float xv = (wid < T_ * N_ && lane < 7) ? x[(size_t)wid * 7 + lane] : 0.f;
    for (int r = wid; r < T_ * N_; r += nw) {
        float xcur = xv;
        int rn = r + nw;
        if (rn < T_ * N_ && lane < 7) xv = x[(size_t)rn * 7 + lane];
        float acc = 0.f;
#pragma unroll
        for (int k = 0; k < 7; ++k) acc = fmaf(rdlane(xcur, k), w[k], acc);
        h1[(size_t)r * 64 + lane] = acc;
        float s = acc * asl, d = acc * adl;
#pragma unroll
        for (int m = 1; m < 32; m <<= 1) { s += __shfl_xor(s, m); d += __shfl_xor(d, m); }
        if ((lane & 31) == 0) {
            a_s[r * 2 + (lane >> 5)] = s;
            a_d[r * 2 + (lane >> 5)] = d;
        }
    }
}

// ---- CSR build: in-degree histogram (frame-affine) ----
__global__ __launch_bounds__(256) void k_deg(const int* __restrict__ ei, int* __restrict__ cnt) {
    int t, local;
    frame_map(blockIdx.x, &t, &local);
    int j = local * 256 + threadIdx.x;
    if (j >= E_) return;
    int dst = ei[t * 2 * E_ + E_ + j];
    atomicAdd(&cnt[t * N_ + dst], 1);
}

// ---- per-frame exclusive scan of (deg+1); shfl-based; writes rowptr and cursor ----
__global__ __launch_bounds__(1024) void k_scan(const int* __restrict__ deg,
                                               int* __restrict__ rowptr,
                                               int* __restrict__ cur) {
    int t = blockIdx.x;
    __shared__ int wsum[16];
    __shared__ int carryS;
    int tid = threadIdx.x, lane = tid & 63, wv = tid >> 6;
    if (tid == 0) { carryS = 0; rowptr[t * (N_ + 1)] = 0; }
    __syncthreads();
    for (int base = 0; base < N_; base += 1024) {
        int i = base + tid;
        int v = (i < N_) ? deg[t * N_ + i] + 1 : 0;
        int s = v;
#pragma unroll
        for (int off = 1; off < 64; off <<= 1) {
            int u = __shfl_up(s, off);
            if (lane >= off) s += u;
        }
        if (lane == 63) wsum[wv] = s;
        __syncthreads();
        if (wv == 0 && lane < 16) {
            int ws = wsum[lane];
            int sc = ws;
#pragma unroll
            for (int off = 1; off < 16; off <<= 1) {
                int u = __shfl_up(sc, off);
                if (lane >= off) sc += u;
            }
            wsum[lane] = sc - ws;   // exclusive offset for wave `lane`
        }
        __syncthreads();
        int incl = s + wsum[wv] + carryS;
        if (i < N_) { rowptr[t * (N_ + 1) + i + 1] = incl; cur[t * N_ + i] = incl - v; }
        __syncthreads();
        if (tid == 1023) carryS = incl;
        __syncthreads();
    }
}

// ---- scatter src ids into CSR col array (frame-affine; self-loops j>=E_) ----
__global__ __launch_bounds__(256) void k_scatter(const int* __restrict__ ei,
                                                 int* __restrict__ cur,
                                                 int* __restrict__ col) {
    int t, local;
    frame_map(blockIdx.x, &t, &local);
    int j = local * 256 + threadIdx.x;
    if (j >= EN_) return;
    int src, dst;
    if (j < E_) { src = ei[t * 2 * E_ + j]; dst = ei[t * 2 * E_ + E_ + j]; }
    else { src = dst = j - E_; }
    int pos = atomicAdd(&cur[t * N_ + dst], 1);
    col[t * EN_ + pos] = src;
}

// ---- gather-aggregate: wave per (t,node), frame-affine.
// Lane e computes exp once per edge; readlane broadcasts (src,p) to all lanes.
// Normalization folded to one divide per node: out = (sum p*h)/(sum p).
template <int HEADS>
__global__ __launch_bounds__(256) void k_agg(
    const int* __restrict__ rowptr, const int* __restrict__ col,
    const float* __restrict__ a_s, const float* __restrict__ a_d,
    const float* __restrict__ hin, const float* __restrict__ bias,
    float* __restrict__ outp) {
    int t, local;
    frame_map(blockIdx.x, &t, &local);
    int lane = threadIdx.x & 63;
    int n = local * 4 + (threadIdx.x >> 6);
    if (n >= N_) return;
    int node = t * N_ + n;
    float ad0 = a_d[node * HEADS];
    float ad1 = (HEADS == 2) ? a_d[node * HEADS + 1] : 0.f;
    int e0 = rowptr[t * (N_ + 1) + n], e1 = rowptr[t * (N_ + 1) + n + 1];
    const int* cb = col + (size_t)t * EN_;
    const float* hb = hin + (size_t)t * N_ * 64;
    const float* ab = a_s + (size_t)t * N_ * HEADS;
    float acc = 0.f, acc2 = 0.f, den0 = 0.f, den1 = 0.f;
    for (int base = e0; base < e1; base += 64) {
        int rem = e1 - base; if (rem > 64) rem = 64;
        int s = 0; float p0 = 0.f, p1 = 0.f;
        if (lane < rem) {
            s = cb[base + lane];
            p0 = expf(lrelu(ab[s * HEADS] + ad0));
            if (HEADS == 2) p1 = expf(lrelu(ab[s * HEADS + 1] + ad1));
        }
        den0 += p0; den1 += p1;
        int k = 0;
        for (; k + 1 < rem; k += 2) {
            int s0 = __builtin_amdgcn_readlane(s, k);
            int s1 = __builtin_amdgcn_readlane(s, k + 1);
            float pk0, pk1;
            if (HEADS == 2) {
                float pa0 = rdlane(p0, k), pa1 = rdlane(p0, k + 1);
                float pb0 = rdlane(p1, k), pb1 = rdlane(p1, k + 1);
                pk0 = (lane < 32) ? pa0 : pb0;
                pk1 = (lane < 32) ? pa1 : pb1;
            } else {
                pk0 = rdlane(p0, k); pk1 = rdlane(p0, k + 1);
            }
            acc  = fmaf(pk0, hb[(size_t)s0 * 64 + lane], acc);
            acc2 = fmaf(pk1, hb[(size_t)s1 * 64 + lane], acc2);
        }
        if (k < rem) {
            int s0 = __builtin_amdgcn_readlane(s, k);
            float pk0 = (HEADS == 2) ? ((lane < 32) ? rdlane(p0, k) : rdlane(p1, k))
                                     : rdlane(p0, k);
            acc = fmaf(pk0, hb[(size_t)s0 * 64 + lane], acc);
        }
    }
    acc += acc2;
#pragma unroll
    for (int m = 1; m < 64; m <<= 1) {
        den0 += __shfl_xor(den0, m);
        if (HEADS == 2) den1 += __shfl_xor(den1, m);
    }
    float den = (HEADS == 2) ? ((lane < 32) ? den0 : den1) : den0;
    outp[(size_t)node * 64 + lane] = elu(acc / (den + 1e-16f) + bias[lane]);
}

// ---- layer 2 GEMM: wave-per-row grid-stride; W2 column in 64 VGPRs; readlane broadcast ----
__global__ __launch_bounds__(256) void k_h2(
    const float* __restrict__ xin, const float* __restrict__ W2,
    const float* __restrict__ as2, const float* __restrict__ ad2,
    float* __restrict__ h2, float* __restrict__ a_s, float* __restrict__ a_d) {
    int lane = threadIdx.x & 63;
    int wid = (blockIdx.x * blockDim.x + threadIdx.x) >> 6;
    int nw = (gridDim.x * blockDim.x) >> 6;
    float w[64];
#pragma unroll
    for (int k = 0; k < 64; ++k) w[k] = W2[k * 64 + lane];
    float asl = as2[lane], adl = ad2[lane];
    float xv = (wid < T_ * N_) ? xin[(size_t)wid * 64 + lane] : 0.f;
    for (int r = wid; r < T_ * N_; r += nw) {
        float xcur = xv;
        int rn = r + nw;
        if (rn < T_ * N_) xv = xin[(size_t)rn * 64 + lane];
        float acc = 0.f;
#pragma unroll
        for (int k = 0; k < 64; ++k) acc = fmaf(rdlane(xcur, k), w[k], acc);
        h2[(size_t)r * 64 + lane] = acc;
        float s = acc * asl, d = acc * adl;
#pragma unroll
        for (int m = 1; m < 64; m <<= 1) { s += __shfl_xor(s, m); d += __shfl_xor(d, m); }
        if (lane == 0) { a_s[r] = s; a_d[r] = d; }
    }
}

// ---- sorted-batch mean-pool over activated node features ----
__global__ void k_pool(const float* __restrict__ hact, const int* __restrict__ batch,
                       float* __restrict__ sums, float* __restrict__ cnt) {
    int wid = (blockIdx.x * blockDim.x + threadIdx.x) >> 6;
    int lane = threadIdx.x & 63;
    const int WPF = (N_ + 63) / 64;
    int t = wid / WPF, w = wid - t * WPF;
    if (t >= T_) return;
    int n0 = w * 64, n1 = min(n0 + 64, N_);
    float acc = 0.f, cacc = 0.f;
    int cur_b = batch[t * N_ + n0];
    for (int n = n0; n < n1; ++n) {
        int b = batch[t * N_ + n];
        if (b != cur_b) {
            atomicAdd(&sums[(t * B_ + cur_b) * 64 + lane], acc);
            if (lane == 0) atomicAdd(&cnt[t * B_ + cur_b], cacc);
            acc = 0.f; cacc = 0.f; cur_b = b;
        }
        acc += hact[(size_t)(t * N_ + n) * 64 + lane];
        cacc += 1.f;
    }
    atomicAdd(&sums[(t * B_ + cur_b) * 64 + lane], acc);
    if (lane == 0) atomicAdd(&cnt[t * B_ + cur_b], cacc);
}

__global__ void k_emb(const float* __restrict__ sums, const float* __restrict__ cnt,
                      float* __restrict__ emb) {
    int idx = blockIdx.x * blockDim.x + threadIdx.x;
    if (idx >= T_ * B_ * 64) return;
    emb[idx] = sums[idx] / fmaxf(cnt[idx >> 6], 1.0f);
}

__global__ void k_gx(const float* __restrict__ emb, const float* __restrict__ Wih,
                     const float* __restrict__ bih, float* __restrict__ gx) {
    int idx = blockIdx.x * blockDim.x + threadIdx.x;
    if (idx >= T_ * B_ * 192) return;
    int tb = idx / 192, g = idx - tb * 192;
    const float* er = emb + tb * 64;
    const float* wr = Wih + g * 64;
    float acc = bih[g];
#pragma unroll
    for (int k = 0; k < 64; ++k) acc = fmaf(er[k], wr[k], acc);
    gx[idx] = acc;
}

// ---- sequential GRU + classifier head (single block); Wh padded stride 65 ----
__global__ __launch_bounds__(1024) void k_gru(
    const float* __restrict__ gx_all, const float* __restrict__ Whh,
    const float* __restrict__ bhh, const float* __restrict__ Wc1,
    const float* __restrict__ bc1, const float* __restrict__ Wc2,
    const float* __restrict__ bc2, float* __restrict__ out) {
    __shared__ float Wh[192 * 65];
    __shared__ float hL[16 * 64];
    __shared__ float gh[16 * 192];
    __shared__ float hid[16 * 32];
    int tid = threadIdx.x;
    for (int i = tid; i < 192 * 64; i += 1024) Wh[(i >> 6) * 65 + (i & 63)] = Whh[i];
    hL[tid] = 0.f;
    __syncthreads();
    for (int t = 0; t < T_; ++t) {
        for (int idx = tid; idx < 16 * 192; idx += 1024) {
            int b = idx / 192, g = idx - b * 192;
            float acc = bhh[g];
            const float* wr = Wh + g * 65;
            const float* hr = hL + b * 64;
#pragma unroll
            for (int k = 0; k < 64; ++k) acc = fmaf(hr[k], wr[k], acc);
            gh[idx] = acc;
        }
        __syncthreads();
        const float* gxt = gx_all + t * 16 * 192;
        {
            int b = tid >> 6, c = tid & 63;
            float xr = gxt[b * 192 + c], xz = gxt[b * 192 + 64 + c], xn = gxt[b * 192 + 128 + c];
            float hr_ = gh[b * 192 + c], hz = gh[b * 192 + 64 + c], hn = gh[b * 192 + 128 + c];
            float r = 1.f / (1.f + expf(-(xr + hr_)));
            float z = 1.f / (1.f + expf(-(xz + hz)));
            float n = tanhf(xn + r * hn);
            hL[tid] = (1.f - z) * n + z * hL[tid];
        }
        __syncthreads();
    }
    for (int idx = tid; idx < 16 * 32; idx += 1024) {
        int b = idx >> 5, j = idx & 31;
        float acc = bc1[j];
#pragma unroll
        for (int k = 0; k < 64; ++k) acc = fmaf(hL[b * 64 + k], Wc1[k * 32 + j], acc);
        hid[idx] = fmaxf(acc, 0.f);
    }
    __syncthreads();
    if (tid < 16) {
        float acc = bc2[0];
#pragma unroll
        for (int k = 0; k < 32; ++k) acc = fmaf(hid[tid * 32 + k], Wc2[k], acc);
        out[tid] = acc;
    }
}

extern "C" void kernel_launch(void* const* d_in, const int* in_sizes, int n_in,
                              void* d_out, int out_size, void* d_ws, size_t ws_size,
                              hipStream_t stream) {
    const float* x   = (const float*)d_in[0];
    const int*   ei  = (const int*)d_in[1];
    const int* batch = (const int*)d_in[2];
    const float* W1  = (const float*)d_in[3];
    const float* as1 = (const float*)d_in[4];
    const float* ad1 = (const float*)d_in[5];
    const float* b1  = (const float*)d_in[6];
    const float* W2  = (const float*)d_in[7];
    const float* as2 = (const float*)d_in[8];
    const float* ad2 = (const float*)d_in[9];
    const float* b2  = (const float*)d_in[10];
    const float* Wih = (const float*)d_in[11];
    const float* Whh = (const float*)d_in[12];
    const float* bih = (const float*)d_in[13];
    const float* bhh = (const float*)d_in[14];
    const float* Wc1 = (const float*)d_in[15];
    const float* bc1 = (const float*)d_in[16];
    const float* Wc2 = (const float*)d_in[17];
    const float* bc2 = (const float*)d_in[18];
    float* out = (float*)d_out;

    float* ws = (float*)d_ws;
    float* hA     = ws;                      // 20,480,000 (h1 / h2)
    float* hX     = hA + 20480000;           // 20,480,000 (activated xin / out2)
    float* a_s    = hX + 20480000;           // 640,000
    float* a_d    = a_s + 640000;            // 640,000
    int*   rowptr = (int*)(a_d + 640000);    // 16*(N+1) = 320,016 (pad to 320,032)
    int*   cur    = rowptr + 320032;         // 320,000 (deg, then cursor)
    int*   col    = cur + 320000;            // 16*EN = 5,440,000
    float* sums   = (float*)(col + 5440000); // 16,384
    float* cnt    = sums + 16384;            // 256
    float* emb    = cnt + 256;               // 16,384
    float* gx     = emb + 16384;             // 49,152

    const int TN = T_ * N_;
    const int BPF_DEG  = (E_ + 255) / 256;   // 1250
    const int BPF_SCAT = (EN_ + 255) / 256;  // 1329
    const int BPF_AGG  = (N_ + 3) / 4;       // 5000 (4 nodes/block)

    hipMemsetAsync(cur, 0, (size_t)320000 * 4, stream);
    hipMemsetAsync(sums, 0, (size_t)(16384 + 256) * 4, stream);

    // ---- CSR build (shared by both layers) ----
    k_deg<<<16 * BPF_DEG, 256, 0, stream>>>(ei, cur);
    k_scan<<<T_, 1024, 0, stream>>>(cur, rowptr, cur);
    k_scatter<<<16 * BPF_SCAT, 256, 0, stream>>>(ei, cur, col);

    // ---- layer 1 ----
    k_h1<<<1024, 256, 0, stream>>>(x, W1, as1, ad1, hA, a_s, a_d);
    k_agg<2><<<16 * BPF_AGG, 256, 0, stream>>>(rowptr, col, a_s, a_d, hA, b1, hX);

    // ---- layer 2 ----
    k_h2<<<1024, 256, 0, stream>>>(hX, W2, as2, ad2, hA, a_s, a_d);
    k_agg<1><<<16 * BPF_AGG, 256, 0, stream>>>(rowptr, col, a_s, a_d, hA, b2, hX);

    // ---- pool + GRU + head ----
    {
        const int WPF = (N_ + 63) / 64;
        int waves = T_ * WPF;
        k_pool<<<(waves * 64 + 255) / 256, 256, 0, stream>>>(hX, batch, sums, cnt);
    }
    k_emb<<<(T_ * B_ * 64 + 255) / 256, 256, 0, stream>>>(sums, cnt, emb);
    k_gx<<<(T_ * B_ * 192 + 255) / 256, 256, 0, stream>>>(emb, Wih, bih, gx);
    k_gru<<<1, 1024, 0, stream>>>(gx, Whh, bhh, Wc1, bc1, Wc2, bc2, out);
}